// Round 3
// baseline (611.750 us; speedup 1.0000x reference)
//
#include <hip/hip_runtime.h>
#include <hip/hip_bf16.h>

typedef __bf16 bf16x8 __attribute__((ext_vector_type(8)));
typedef __bf16 bf16x4 __attribute__((ext_vector_type(4)));
typedef float f32x4 __attribute__((ext_vector_type(4)));

// Direct global->LDS async copy, 16B per lane. LDS dest must be the
// wave-uniform base; HW places lane i at base + i*16B. Global src is per-lane.
__device__ __forceinline__ void async_copy16(__bf16* lds_base, const __bf16* g) {
  __builtin_amdgcn_global_load_lds(
      (const __attribute__((address_space(1))) void*)g,
      (__attribute__((address_space(3))) void*)lds_base, 16, 0, 0);
}

// ---------------- f32 -> bf16 conversion (4 elems/thread) ----------------
__global__ __launch_bounds__(256) void cvt_bf16(const float* __restrict__ in,
                                                __bf16* __restrict__ out, int n4) {
  int i = blockIdx.x * 256 + threadIdx.x;
  if (i >= n4) return;
  float4 v = ((const float4*)in)[i];
  bf16x4 o;
  o.x = (__bf16)v.x; o.y = (__bf16)v.y; o.z = (__bf16)v.z; o.w = (__bf16)v.w;
  ((bf16x4*)out)[i] = o;
}

// ---------------- small GEMM (kept for kv): 128x128 tile, m97 pattern ----
template<bool STORE_BF16>
__global__ __launch_bounds__(256) void gemm_bt(const __bf16* __restrict__ A,
                                               const __bf16* __restrict__ Bw,
                                               const float* __restrict__ bias,
                                               void* __restrict__ Cp,
                                               int M, int N, int K) {
  __shared__ __align__(16) __bf16 sA[128 * 64];
  __shared__ __align__(16) __bf16 sB[128 * 64];
  const int tid = threadIdx.x;
  const int lane = tid & 63;
  const int w = tid >> 6;
  const int wr = w >> 1, wc = w & 1;
  const int l15 = lane & 15, q4 = lane >> 4;
  const int bm = blockIdx.x, bn = blockIdx.y;

  f32x4 acc[4][4] = {};

  for (int k0 = 0; k0 < K; k0 += 64) {
    __syncthreads();
#pragma unroll
    for (int it = 0; it < 4; ++it) {
      int chunk = it * 256 + tid;
      int row = chunk >> 3, c8 = chunk & 7;
      int ldsbase = (it * 256 + w * 64) * 8;
      async_copy16(sA + ldsbase, A + (size_t)(bm * 128 + row) * K + k0 + c8 * 8);
      async_copy16(sB + ldsbase, Bw + (size_t)(bn * 128 + row) * K + k0 + c8 * 8);
    }
    __syncthreads();
#pragma unroll
    for (int kk = 0; kk < 2; ++kk) {
      bf16x8 af[4], bfr[4];
#pragma unroll
      for (int i = 0; i < 4; ++i)
        af[i] = *(const bf16x8*)(sA + (wr * 64 + i * 16 + l15) * 64 + kk * 32 + q4 * 8);
#pragma unroll
      for (int j = 0; j < 4; ++j)
        bfr[j] = *(const bf16x8*)(sB + (wc * 64 + j * 16 + l15) * 64 + kk * 32 + q4 * 8);
#pragma unroll
      for (int i = 0; i < 4; ++i)
#pragma unroll
        for (int j = 0; j < 4; ++j)
          acc[i][j] = __builtin_amdgcn_mfma_f32_16x16x32_bf16(af[i], bfr[j], acc[i][j], 0, 0, 0);
    }
  }
#pragma unroll
  for (int j = 0; j < 4; ++j) {
    const int col = bn * 128 + wc * 64 + j * 16 + l15;
    const float bv = bias[col];
#pragma unroll
    for (int i = 0; i < 4; ++i) {
      const int row0 = bm * 128 + wr * 64 + i * 16 + q4 * 4;
#pragma unroll
      for (int r = 0; r < 4; ++r) {
        float v = acc[i][j][r] + bv;
        size_t off = (size_t)(row0 + r) * N + col;
        if (STORE_BF16) ((__bf16*)Cp)[off] = (__bf16)v;
        else            ((float*)Cp)[off]  = v;
      }
    }
  }
}

// ---------------- big GEMM: 256x256 tile, BK=64, 4 phases, reads 8/4/8/4 --
// 512 threads = 8 waves (2M x 4N); per-wave output 128x64. LDS: 2 buffers x
// (A 256x64 + B 256x64) bf16 = 128 KiB (one smem overlay; epilogue reuses it).
// XOR-8 swizzle on 16B chunks: logical chunk c of row r at phys c^(r&7)
// (pre-swizzled global source; gload_lds dest linear; swizzled ds_read).
// Phases (16 MFMA each): ph0 a(m0-3) reads + stage Bh1(t+1); ph1 b1 reads +
// stage Ah1(t+1); ph2 a(m4-7) + stage Ah0(t+2); ph3 stage Bh0(t+2) +
// vmcnt(4) + prefetch next tile's b0 frags after the barrier.
// Ledger: at ph3's vmcnt(4), outstanding = {Ah0,Bh0,Bh1,Ah1}(t+1) +
// {Ah0,Bh0}(t+2) = 12 loads; keep 4 -> all of t+1 drained => b0(t+1)
// readable post-barrier, and tile t+1 fully resident at its ph0.
template<int KK, int EPI>
__global__ __launch_bounds__(512, 2) void gemm_big(const __bf16* __restrict__ A,
                                                   const __bf16* __restrict__ Bw,
                                                   const float* __restrict__ bias,
                                                   void* __restrict__ Cp,
                                                   const float* __restrict__ g,
                                                   const float* __restrict__ bt,
                                                   int N) {
  constexpr int NT = KK / 64;
  static_assert(NT >= 3, "need >=3 K-tiles");
  __shared__ __align__(16) __bf16 smem[4 * 256 * 64];   // 128 KiB overlay
  const int tid = threadIdx.x;
  const int lane = tid & 63;
  const int w = tid >> 6;
  const int wr = w >> 2, wc = w & 3;
  const int l15 = lane & 15, q4 = lane >> 4;

  // XCD-chunked swizzle (grid fixed at dim3(128,4), 512 = 8*64 blocks):
  // each XCD gets 64 consecutive sbids, bn-fastest -> A-panel sharers adjacent.
  const int bid = (blockIdx.y << 7) + blockIdx.x;
  const int sbid = (bid & 7) * 64 + (bid >> 3);
  const int bm = sbid >> 2, bn = sbid & 3;

  // staging geometry: per issue, a wave covers 8 consecutive rows x 8 chunks.
  const int rl = lane >> 3;            // row within the wave's 8-row stripe
  const int cs = (lane & 7) ^ rl;      // pre-swizzled source chunk (phys=lane&7)
  const __bf16* Ag = A + (size_t)(bm * 256) * KK + cs * 8;
  const __bf16* Bg = Bw + (size_t)(bn * 256) * KK + cs * 8;
  const int gbA = w * 8;                        // A half h: +h*64; issue1: +128
  const int gbB = (w & 3) * 8 + (w >> 2) * 64;  // B half h: +h*32; issue1: +128

  auto sAbuf = [&](int bb) { return smem + bb * 16384; };
  auto sBbuf = [&](int bb) { return smem + 32768 + bb * 16384; };

  auto STAGE_A = [&](int bb, int t, int h) {
    int gb = gbA + h * 64;
    async_copy16(sAbuf(bb) + gb * 64,         Ag + (size_t)(gb + rl) * KK + t * 64);
    async_copy16(sAbuf(bb) + (gb + 128) * 64, Ag + (size_t)(gb + 128 + rl) * KK + t * 64);
  };
  auto STAGE_B = [&](int bb, int t, int h) {
    int gb = gbB + h * 32;
    async_copy16(sBbuf(bb) + gb * 64,         Bg + (size_t)(gb + rl) * KK + t * 64);
    async_copy16(sBbuf(bb) + (gb + 128) * 64, Bg + (size_t)(gb + 128 + rl) * KK + t * 64);
  };

  // ds_read fragment addressing: frag rows have row&7 == l15&7, so
  // phys chunk = (kk*4+q4) ^ (l15&7).
  const int pc0 = ((q4) ^ (l15 & 7)) * 8;
  const int pc1 = ((4 + q4) ^ (l15 & 7)) * 8;
  const int arow0 = (wr * 128 + l15) * 64;
  const int brow0 = (wc * 64 + l15) * 64;

  f32x4 acc[8][4] = {};
  bf16x8 b0[2][2];   // loop-carried: current tile's B n0,n1 fragments

  // prologue: tile0 fully + tile1 h0s; drain tile0 (keep 4 in flight)
  STAGE_A(0, 0, 0); STAGE_B(0, 0, 0); STAGE_B(0, 0, 1); STAGE_A(0, 0, 1);
  STAGE_A(1, 1, 0); STAGE_B(1, 1, 0);
  asm volatile("s_waitcnt vmcnt(4)" ::: "memory");
  __builtin_amdgcn_s_barrier();
  __builtin_amdgcn_sched_barrier(0);
#pragma unroll
  for (int n = 0; n < 2; ++n) {
    b0[n][0] = *(const bf16x8*)(sBbuf(0) + brow0 + n * 1024 + pc0);
    b0[n][1] = *(const bf16x8*)(sBbuf(0) + brow0 + n * 1024 + pc1);
  }

#pragma unroll 2
  for (int t = 0; t < NT; ++t) {
    const int cb = t & 1, nb = cb ^ 1;
    const __bf16* sAc = sAbuf(cb);
    const __bf16* sBc = sBbuf(cb);
    bf16x8 a[4][2], b1[2][2];

    // ---- ph0: read a(m0-3), stage Bh1(t+1), MFMA (m0,n0) ----
#pragma unroll
    for (int m = 0; m < 4; ++m) {
      a[m][0] = *(const bf16x8*)(sAc + arow0 + m * 1024 + pc0);
      a[m][1] = *(const bf16x8*)(sAc + arow0 + m * 1024 + pc1);
    }
    if (t + 1 < NT) STAGE_B(nb, t + 1, 1);
    __builtin_amdgcn_s_barrier();
    asm volatile("s_waitcnt lgkmcnt(0)" ::: "memory");
    __builtin_amdgcn_sched_barrier(0);
    __builtin_amdgcn_s_setprio(1);
#pragma unroll
    for (int m = 0; m < 4; ++m)
#pragma unroll
      for (int n = 0; n < 2; ++n) {
        acc[m][n] = __builtin_amdgcn_mfma_f32_16x16x32_bf16(a[m][0], b0[n][0], acc[m][n], 0, 0, 0);
        acc[m][n] = __builtin_amdgcn_mfma_f32_16x16x32_bf16(a[m][1], b0[n][1], acc[m][n], 0, 0, 0);
      }
    __builtin_amdgcn_s_setprio(0);
    __builtin_amdgcn_s_barrier();
    __builtin_amdgcn_sched_barrier(0);

    // ---- ph1: read b(n2-3), stage Ah1(t+1), MFMA (m0,n1) ----
#pragma unroll
    for (int n = 0; n < 2; ++n) {
      b1[n][0] = *(const bf16x8*)(sBc + brow0 + (2 + n) * 1024 + pc0);
      b1[n][1] = *(const bf16x8*)(sBc + brow0 + (2 + n) * 1024 + pc1);
    }
    if (t + 1 < NT) STAGE_A(nb, t + 1, 1);
    __builtin_amdgcn_s_barrier();
    asm volatile("s_waitcnt lgkmcnt(0)" ::: "memory");
    __builtin_amdgcn_sched_barrier(0);
    __builtin_amdgcn_s_setprio(1);
#pragma unroll
    for (int m = 0; m < 4; ++m)
#pragma unroll
      for (int n = 0; n < 2; ++n) {
        acc[m][2 + n] = __builtin_amdgcn_mfma_f32_16x16x32_bf16(a[m][0], b1[n][0], acc[m][2 + n], 0, 0, 0);
        acc[m][2 + n] = __builtin_amdgcn_mfma_f32_16x16x32_bf16(a[m][1], b1[n][1], acc[m][2 + n], 0, 0, 0);
      }
    __builtin_amdgcn_s_setprio(0);
    __builtin_amdgcn_s_barrier();
    __builtin_amdgcn_sched_barrier(0);

    // ---- ph2: read a(m4-7), stage Ah0(t+2), MFMA (m1,n0) ----
#pragma unroll
    for (int m = 0; m < 4; ++m) {
      a[m][0] = *(const bf16x8*)(sAc + arow0 + (4 + m) * 1024 + pc0);
      a[m][1] = *(const bf16x8*)(sAc + arow0 + (4 + m) * 1024 + pc1);
    }
    if (t + 2 < NT) STAGE_A(cb, t + 2, 0);
    __builtin_amdgcn_s_barrier();
    asm volatile("s_waitcnt lgkmcnt(0)" ::: "memory");
    __builtin_amdgcn_sched_barrier(0);
    __builtin_amdgcn_s_setprio(1);
#pragma unroll
    for (int m = 0; m < 4; ++m)
#pragma unroll
      for (int n = 0; n < 2; ++n) {
        acc[4 + m][n] = __builtin_amdgcn_mfma_f32_16x16x32_bf16(a[m][0], b0[n][0], acc[4 + m][n], 0, 0, 0);
        acc[4 + m][n] = __builtin_amdgcn_mfma_f32_16x16x32_bf16(a[m][1], b0[n][1], acc[4 + m][n], 0, 0, 0);
      }
    __builtin_amdgcn_s_setprio(0);
    __builtin_amdgcn_s_barrier();
    __builtin_amdgcn_sched_barrier(0);

    // ---- ph3: stage Bh0(t+2), counted wait, prefetch b0(t+1), MFMA (m1,n1) --
    if (t + 2 < NT) STAGE_B(cb, t + 2, 0);
    if (t + 2 < NT)      { asm volatile("s_waitcnt vmcnt(4)" ::: "memory"); }
    else if (t + 1 < NT) { asm volatile("s_waitcnt vmcnt(0)" ::: "memory"); }
    __builtin_amdgcn_s_barrier();
    __builtin_amdgcn_sched_barrier(0);
    if (t + 1 < NT) {
      const __bf16* sBn = sBbuf(nb);
#pragma unroll
      for (int n = 0; n < 2; ++n) {
        b0[n][0] = *(const bf16x8*)(sBn + brow0 + n * 1024 + pc0);
        b0[n][1] = *(const bf16x8*)(sBn + brow0 + n * 1024 + pc1);
      }
    }
    __builtin_amdgcn_s_setprio(1);
#pragma unroll
    for (int m = 0; m < 4; ++m)
#pragma unroll
      for (int n = 0; n < 2; ++n) {
        acc[4 + m][2 + n] = __builtin_amdgcn_mfma_f32_16x16x32_bf16(a[m][0], b1[n][0], acc[4 + m][2 + n], 0, 0, 0);
        acc[4 + m][2 + n] = __builtin_amdgcn_mfma_f32_16x16x32_bf16(a[m][1], b1[n][1], acc[4 + m][2 + n], 0, 0, 0);
      }
    __builtin_amdgcn_s_setprio(0);
    __builtin_amdgcn_s_barrier();
    __builtin_amdgcn_sched_barrier(0);
  }

  if (EPI == 0) {
    // plain f32 store + bias
#pragma unroll
    for (int n = 0; n < 4; ++n) {
      const int col = bn * 256 + wc * 64 + n * 16 + l15;
      const float bv = bias[col];
#pragma unroll
      for (int m = 0; m < 8; ++m) {
        const int row0 = bm * 256 + wr * 128 + m * 16 + q4 * 4;
#pragma unroll
        for (int r = 0; r < 4; ++r)
          ((float*)Cp)[(size_t)(row0 + r) * N + col] = acc[m][n][r] + bv;
      }
    }
  } else {
    // fused q epilogue via LDS transpose. smem reused as [128][256] f32 with
    // 16B-chunk XOR swizzle (chunk ^= row&7). Two passes over row-halves:
    // waves of that half write biased acc; then each thread owns one full
    // (row, head) => serial LN (no shfl), adjacent-pair RoPE (no shfl),
    // coalesced bf16x8 stores to Q (b,nh,s1,d).
    float* sf = (float*)smem;
    float bv[4];
#pragma unroll
    for (int n = 0; n < 4; ++n) bv[n] = bias[bn * 256 + wc * 64 + n * 16 + l15];
    const int hh = tid & 3, rr = tid >> 2;     // read-side task
    const int nh = bn * 4 + hh;
    const int rkey = rr & 7;
#pragma unroll
    for (int p = 0; p < 2; ++p) {
      __builtin_amdgcn_s_barrier();
      if (wr == p) {
#pragma unroll
        for (int m = 0; m < 8; ++m)
#pragma unroll
          for (int r = 0; r < 4; ++r) {
            const int row = m * 16 + q4 * 4 + r;
            const int key = row & 7;
#pragma unroll
            for (int n = 0; n < 4; ++n) {
              const int chunk = wc * 16 + n * 4 + (l15 >> 2);
              sf[row * 256 + ((chunk ^ key) << 2) + (l15 & 3)] = acc[m][n][r] + bv[n];
            }
          }
      }
      __builtin_amdgcn_s_barrier();
      const int grow = bm * 256 + p * 128 + rr;
      const int s1 = grow & 4095, bidx = grow >> 12;
      const float hp = (float)(s1 >> 6), wp = (float)(s1 & 63);
      const float* rbase = sf + rr * 256;
      f32x4 vv[16];
      float sum = 0.f;
#pragma unroll
      for (int j = 0; j < 16; ++j) {
        vv[j] = *(const f32x4*)(rbase + (((hh * 16 + j) ^ rkey) << 2));
#pragma unroll
        for (int e = 0; e < 4; ++e) sum += vv[j][e];
      }
      const float mu = sum * (1.f / 64.f);
      float sq = 0.f;
#pragma unroll
      for (int j = 0; j < 16; ++j)
#pragma unroll
        for (int e = 0; e < 4; ++e) { float d = vv[j][e] - mu; sq += d * d; }
      const float rs = rsqrtf(sq * (1.f / 64.f) + 1e-6f);
      __bf16* Qrow = (__bf16*)Cp + (((size_t)bidx * 16 + nh) * 4096 + s1) * 64;
#pragma unroll
      for (int j2 = 0; j2 < 8; ++j2) {
        bf16x8 o;
#pragma unroll
        for (int h2 = 0; h2 < 2; ++h2) {
          const int j = j2 * 2 + h2;
          const f32x4 gv  = *(const f32x4*)(g + j * 4);
          const f32x4 btv = *(const f32x4*)(bt + j * 4);
          const float x0 = (vv[j][0] - mu) * rs * gv[0] + btv[0];
          const float x1 = (vv[j][1] - mu) * rs * gv[1] + btv[1];
          const float x2 = (vv[j][2] - mu) * rs * gv[2] + btv[2];
          const float x3 = (vv[j][3] - mu) * rs * gv[3] + btv[3];
          const float inv = __expf(-(float)j * 0.5756462732485114f);
          const float a0 = hp * inv, a1 = wp * inv;
          const float c0 = __cosf(a0), s0 = __sinf(a0);
          const float c1 = __cosf(a1), s1v = __sinf(a1);
          o[h2 * 4 + 0] = (__bf16)((x0 * c0 - x1 * s0) * 0.125f);
          o[h2 * 4 + 1] = (__bf16)((x0 * s0 + x1 * c0) * 0.125f);
          o[h2 * 4 + 2] = (__bf16)((x2 * c1 - x3 * s1v) * 0.125f);
          o[h2 * 4 + 3] = (__bf16)((x2 * s1v + x3 * c1) * 0.125f);
        }
        *(bf16x8*)(Qrow + j2 * 8) = o;
      }
    }
  }
}

// ---------------- kv epilogue: LN(k) -> K (b,nh,s2,d); v -> V^T (b,nh,d,s2)
__global__ __launch_bounds__(256) void kv_epilogue(const float* __restrict__ kv,
                                                   const float* __restrict__ g,
                                                   const float* __restrict__ bta,
                                                   __bf16* __restrict__ Kd,
                                                   __bf16* __restrict__ VT) {
  const int lane = threadIdx.x & 63;
  const int vec = blockIdx.x * 4 + (threadIdx.x >> 6);
  const int nh = vec & 15;
  const int sv = (vec >> 4) & 1;
  const int row = vec >> 5;
  const int b = row >> 8, s2 = row & 255;
  float v = kv[(size_t)row * 2048 + sv * 1024 + nh * 64 + lane];
  if (sv == 0) {
    float mu = v;
#pragma unroll
    for (int o = 32; o; o >>= 1) mu += __shfl_xor(mu, o);
    mu *= (1.f / 64.f);
    float d = v - mu;
    float va = d * d;
#pragma unroll
    for (int o = 32; o; o >>= 1) va += __shfl_xor(va, o);
    va *= (1.f / 64.f);
    float xn = d * rsqrtf(va + 1e-6f) * g[lane] + bta[lane];
    Kd[(((size_t)b * 16 + nh) * 256 + s2) * 64 + lane] = (__bf16)xn;
  } else {
    VT[(((size_t)b * 16 + nh) * 64 + lane) * 256 + s2] = (__bf16)v;
  }
}

// ---------------- fused attention: per (b,nh, 64-row q tile) --------------
__global__ __launch_bounds__(256) void attn_kernel(const __bf16* __restrict__ Q,
                                                   const __bf16* __restrict__ Kd,
                                                   const __bf16* __restrict__ VT,
                                                   __bf16* __restrict__ O) {
  __shared__ __align__(16) __bf16 sK[256 * 64];
  __shared__ __align__(16) __bf16 sV[64 * 256];
  const int tid = threadIdx.x, lane = tid & 63, w = tid >> 6;
  const int l15 = lane & 15, q4 = lane >> 4;
  const int s7 = l15 & 7;
  const int bh = blockIdx.y;
  const int m0 = blockIdx.x * 64;
  const __bf16* Kg = Kd + (size_t)bh * 256 * 64;
  const __bf16* Vg = VT + (size_t)bh * 64 * 256;
  const __bf16* Qg = Q + ((size_t)bh * 4096 + m0) * 64;
#pragma unroll
  for (int it = 0; it < 8; ++it) {
    int c = it * 256 + tid;
    int kr = c >> 3, kh = c & 7;
    *(uint4*)(sK + kr * 64 + ((kh ^ (kr & 7)) * 8)) = *(const uint4*)(Kg + c * 8);
    int vr = c >> 5, vh = c & 31;
    *(uint4*)(sV + vr * 256 + ((vh ^ (vr & 7)) * 8)) = *(const uint4*)(Vg + c * 8);
  }
  bf16x8 qf0 = *(const bf16x8*)(Qg + (w * 16 + l15) * 64 + q4 * 8);
  bf16x8 qf1 = *(const bf16x8*)(Qg + (w * 16 + l15) * 64 + 32 + q4 * 8);
  __syncthreads();
  f32x4 sacc[16] = {};
#pragma unroll
  for (int mt = 0; mt < 16; ++mt) {
    bf16x8 a0 = *(const bf16x8*)(sK + (mt * 16 + l15) * 64 + ((q4 ^ s7) * 8));
    bf16x8 a1 = *(const bf16x8*)(sK + (mt * 16 + l15) * 64 + (((4 + q4) ^ s7) * 8));
    sacc[mt] = __builtin_amdgcn_mfma_f32_16x16x32_bf16(a0, qf0, sacc[mt], 0, 0, 0);
    sacc[mt] = __builtin_amdgcn_mfma_f32_16x16x32_bf16(a1, qf1, sacc[mt], 0, 0, 0);
  }
  __syncthreads();
  float mx = -1e30f;
#pragma unroll
  for (int mt = 0; mt < 16; ++mt)
#pragma unroll
    for (int r = 0; r < 4; ++r) mx = fmaxf(mx, sacc[mt][r]);
  mx = fmaxf(mx, __shfl_xor(mx, 16));
  mx = fmaxf(mx, __shfl_xor(mx, 32));
  float l = 0.f;
#pragma unroll
  for (int mt = 0; mt < 16; ++mt)
#pragma unroll
    for (int r = 0; r < 4; ++r) {
      float p = __expf(sacc[mt][r] - mx);
      sacc[mt][r] = p;
      l += p;
    }
  l += __shfl_xor(l, 16);
  l += __shfl_xor(l, 32);
  const float linv = 1.f / l;
#pragma unroll
  for (int mt = 0; mt < 16; ++mt) {
    bf16x4 pk;
    pk.x = (__bf16)(sacc[mt][0] * linv);
    pk.y = (__bf16)(sacc[mt][1] * linv);
    pk.z = (__bf16)(sacc[mt][2] * linv);
    pk.w = (__bf16)(sacc[mt][3] * linv);
    int chunk = mt * 2 + (q4 >> 1);
    *(bf16x4*)(sK + (w * 16 + l15) * 256 + ((chunk ^ s7) * 8) + (q4 & 1) * 4) = pk;
  }
  f32x4 oacc[4] = {};
#pragma unroll
  for (int ks = 0; ks < 8; ++ks) {
    int phys = ((ks * 4 + q4) ^ s7) * 8;
    bf16x8 a = *(const bf16x8*)(sK + (w * 16 + l15) * 256 + phys);
#pragma unroll
    for (int j = 0; j < 4; ++j) {
      bf16x8 b = *(const bf16x8*)(sV + (j * 16 + l15) * 256 + phys);
      oacc[j] = __builtin_amdgcn_mfma_f32_16x16x32_bf16(a, b, oacc[j], 0, 0, 0);
    }
  }
  const int b = bh >> 4, nh = bh & 15;
#pragma unroll
  for (int j = 0; j < 4; ++j)
#pragma unroll
    for (int r = 0; r < 4; ++r) {
      size_t off = ((size_t)b * 4096 + m0 + w * 16 + q4 * 4 + r) * 1024
                 + nh * 64 + j * 16 + l15;
      O[off] = (__bf16)oacc[j][r];
    }
}

extern "C" void kernel_launch(void* const* d_in, const int* in_sizes, int n_in,
                              void* d_out, int out_size, void* d_ws, size_t ws_size,
                              hipStream_t stream) {
  const float* x    = (const float*)d_in[0];
  const float* y    = (const float*)d_in[1];
  const float* wq   = (const float*)d_in[2];
  const float* bq   = (const float*)d_in[3];
  const float* wkv  = (const float*)d_in[4];
  const float* bkv  = (const float*)d_in[5];
  const float* wo   = (const float*)d_in[6];
  const float* bo   = (const float*)d_in[7];
  const float* qng  = (const float*)d_in[8];
  const float* qnb  = (const float*)d_in[9];
  const float* kng  = (const float*)d_in[10];
  const float* knb  = (const float*)d_in[11];
  float* out = (float*)d_out;

  char* ws = (char*)d_ws;
  size_t off = 0;
  auto take = [&](size_t bytes) { char* p = ws + off; off += (bytes + 255) & ~(size_t)255; return p; };
  __bf16* xb   = (__bf16*)take((size_t)32768 * 1024 * 2);
  char*  reg1  = take((size_t)32768 * 1024 * 2);
  __bf16* Qb   = (__bf16*)take((size_t)32768 * 1024 * 2);
  __bf16* yb   = (__bf16*)take((size_t)2048 * 2048 * 2);
  __bf16* wqb  = (__bf16*)take((size_t)1024 * 1024 * 2);
  __bf16* wkvb = (__bf16*)take((size_t)2048 * 2048 * 2);
  __bf16* wob  = (__bf16*)take((size_t)1024 * 1024 * 2);
  __bf16* Kb   = (__bf16*)take((size_t)128 * 256 * 64 * 2);
  __bf16* VTb  = (__bf16*)take((size_t)128 * 64 * 256 * 2);
  float*  kvf  = (float*)reg1;
  __bf16* aout = xb;

  cvt_bf16<<<32768, 256, 0, stream>>>(x,   xb,   8388608);
  cvt_bf16<<<4096,  256, 0, stream>>>(y,   yb,   1048576);
  cvt_bf16<<<1024,  256, 0, stream>>>(wq,  wqb,  262144);
  cvt_bf16<<<4096,  256, 0, stream>>>(wkv, wkvb, 1048576);
  cvt_bf16<<<1024,  256, 0, stream>>>(wo,  wob,  262144);

  // kv = y @ wkv^T + bkv  (f32 out), then LN(k)->K, v->V^T
  gemm_bt<false><<<dim3(16, 16), 256, 0, stream>>>(yb, wkvb, bkv, kvf, 2048, 2048, 2048);
  kv_epilogue<<<16384, 256, 0, stream>>>(kvf, kng, knb, Kb, VTb);

  // Q = RoPE(LN(x @ wq^T + bq)) * SCALE, fused in the GEMM epilogue
  gemm_big<1024, 2><<<dim3(128, 4), 512, 0, stream>>>(xb, wqb, bq, Qb, qng, qnb, 1024);

  // fused attention -> aout (b,s1,nh*hd) bf16
  attn_kernel<<<dim3(64, 128), 256, 0, stream>>>(Qb, Kb, VTb, aout);

  // out = aout @ wo^T + bo (f32 out)
  gemm_big<1024, 0><<<dim3(128, 4), 512, 0, stream>>>(aout, wob, bo, out, nullptr, nullptr, 1024);
}